// Round 2
// baseline (377.509 us; speedup 1.0000x reference)
//
#include <hip/hip_runtime.h>

#define GRIDN 256
#define BINS1 32          // bins per axis
#define BINSHIFT 3        // 8 cells per bin per axis
#define NBINS (BINS1 * BINS1 * BINS1)

// ---------- shared helpers ----------

__device__ __forceinline__ int cell_guess(float c) {
    // approximate cell index, used ONLY for spatial binning (locality), not correctness
    float t = (c + 0.64f) * 200.0f;
    int i = (int)t;
    return min(max(i, 0), GRIDN - 1);
}

// exact jnp.searchsorted(p, c, side='left') + clip semantics
__device__ __forceinline__ void dim_interp(float c, const float* __restrict__ p,
                                           int& il, int& ir, float& dl, float& dr) {
    const float SCALE = 0.005f;
    const float OFFSET = -0.64f;
    float t = (c - OFFSET) * (1.0f / SCALE);
    int i = (int)ceilf(t);
    i = min(max(i, 0), GRIDN - 1);
    while (i < GRIDN - 1 && p[i] < c) ++i;
    while (i > 0 && p[i - 1] >= c) --i;
    ir = i;
    il = max(i - 1, 0);
    dl = fmaxf(c - p[il], 0.0f);
    dr = fmaxf(p[ir] - c, 0.0f);
    if (dl == 0.0f && dr == 0.0f) { dl = 1.0f; dr = 1.0f; }
}

__device__ __forceinline__ float interp_point(float cx, float cy, float cz,
                                              const float* __restrict__ values,
                                              const float* __restrict__ px,
                                              const float* __restrict__ py,
                                              const float* __restrict__ pz) {
    int ixl, ixr, iyl, iyr, izl, izr;
    float dxl, dxr, dyl, dyr, dzl, dzr;
    dim_interp(cx, px, ixl, ixr, dxl, dxr);
    dim_interp(cy, py, iyl, iyr, dyl, dyr);
    dim_interp(cz, pz, izl, izr, dzl, dzr);

    int bxl = ixl << 16, bxr = ixr << 16;
    int byl = iyl << 8,  byr = iyr << 8;

    float v000 = values[bxl + byl + izl];
    float v001 = values[bxl + byl + izr];
    float v010 = values[bxl + byr + izl];
    float v011 = values[bxl + byr + izr];
    float v100 = values[bxr + byl + izl];
    float v101 = values[bxr + byl + izr];
    float v110 = values[bxr + byr + izl];
    float v111 = values[bxr + byr + izr];

    float num =
        v000 * (dxr * dyr * dzr) +
        v001 * (dxr * dyr * dzl) +
        v010 * (dxr * dyl * dzr) +
        v011 * (dxr * dyl * dzl) +
        v100 * (dxl * dyr * dzr) +
        v101 * (dxl * dyr * dzl) +
        v110 * (dxl * dyl * dzr) +
        v111 * (dxl * dyl * dzl);

    float den = (dxl + dxr) * (dyl + dyr) * (dzl + dzr);
    return num / den;
}

// ---------- pass 1: count + keys ----------

__global__ void bin_count(const float* __restrict__ x, int K,
                          unsigned* __restrict__ counts, int* __restrict__ keys) {
    int i = blockIdx.x * blockDim.x + threadIdx.x;
    if (i >= K) return;
    int bx = cell_guess(x[3 * i + 0]) >> BINSHIFT;
    int by = cell_guess(x[3 * i + 1]) >> BINSHIFT;
    int bz = cell_guess(x[3 * i + 2]) >> BINSHIFT;
    int bid = (bx * BINS1 + by) * BINS1 + bz;
    keys[i] = bid;
    atomicAdd(&counts[bid], 1u);
}

// ---------- pass 2: exclusive scan over NBINS counts (single block) ----------

__global__ void bin_scan(unsigned* __restrict__ counts) {
    __shared__ unsigned s[1024];
    int tid = threadIdx.x;
    unsigned running = 0;
    for (int base = 0; base < NBINS; base += 1024) {
        unsigned c = counts[base + tid];
        s[tid] = c;
        __syncthreads();
        for (int off = 1; off < 1024; off <<= 1) {
            unsigned v = (tid >= off) ? s[tid - off] : 0u;
            __syncthreads();
            s[tid] += v;
            __syncthreads();
        }
        counts[base + tid] = running + s[tid] - c;  // exclusive prefix
        running += s[1023];
        __syncthreads();
    }
}

// ---------- pass 3: scatter permutation ----------

__global__ void bin_scatter(const int* __restrict__ keys, int K,
                            unsigned* __restrict__ cursors, int* __restrict__ perm) {
    int i = blockIdx.x * blockDim.x + threadIdx.x;
    if (i >= K) return;
    unsigned pos = atomicAdd(&cursors[keys[i]], 1u);
    perm[pos] = i;
}

// ---------- pass 4: interpolation in bin-sorted order ----------

__global__ void trilerp_sorted(const float* __restrict__ x,
                               const float* __restrict__ values,
                               const float* __restrict__ px,
                               const float* __restrict__ py,
                               const float* __restrict__ pz,
                               const int* __restrict__ perm,
                               float* __restrict__ out, int K) {
    // bijective XCD swizzle (m204): contiguous bin-sorted chunk per XCD -> L2 locality
    int nb = gridDim.x;
    int b = blockIdx.x;
    int q = nb >> 3, r = nb & 7;
    int xcd = b & 7, seq = b >> 3;
    int swb = (xcd < r ? xcd * (q + 1) : r * (q + 1) + (xcd - r) * q) + seq;

    int t = swb * blockDim.x + threadIdx.x;
    if (t >= K) return;
    int j = perm[t];
    float cx = x[3 * j + 0];
    float cy = x[3 * j + 1];
    float cz = x[3 * j + 2];
    out[j] = interp_point(cx, cy, cz, values, px, py, pz);
}

// ---------- fallback: direct (round-1) kernel ----------

__global__ void trilerp_direct(const float* __restrict__ x,
                               const float* __restrict__ values,
                               const float* __restrict__ px,
                               const float* __restrict__ py,
                               const float* __restrict__ pz,
                               float* __restrict__ out, int K) {
    int i = blockIdx.x * blockDim.x + threadIdx.x;
    if (i >= K) return;
    out[i] = interp_point(x[3 * i], x[3 * i + 1], x[3 * i + 2], values, px, py, pz);
}

extern "C" void kernel_launch(void* const* d_in, const int* in_sizes, int n_in,
                              void* d_out, int out_size, void* d_ws, size_t ws_size,
                              hipStream_t stream) {
    const float* x      = (const float*)d_in[0];
    const float* values = (const float*)d_in[1];
    const float* px     = (const float*)d_in[2];
    const float* py     = (const float*)d_in[3];
    const float* pz     = (const float*)d_in[4];
    float* out = (float*)d_out;

    int K = in_sizes[0] / 3;
    const int block = 256;
    int grid = (K + block - 1) / block;

    size_t counts_bytes = (size_t)NBINS * 4;
    size_t keys_bytes   = (size_t)K * 4;
    size_t perm_bytes   = (size_t)K * 4;
    size_t need = counts_bytes + keys_bytes + perm_bytes;

    if (ws_size < need) {
        trilerp_direct<<<grid, block, 0, stream>>>(x, values, px, py, pz, out, K);
        return;
    }

    unsigned* counts = (unsigned*)d_ws;
    int* keys = (int*)((char*)d_ws + counts_bytes);
    int* perm = (int*)((char*)d_ws + counts_bytes + keys_bytes);

    hipMemsetAsync(counts, 0, counts_bytes, stream);
    bin_count<<<grid, block, 0, stream>>>(x, K, counts, keys);
    bin_scan<<<1, 1024, 0, stream>>>(counts);
    bin_scatter<<<grid, block, 0, stream>>>(keys, K, counts, perm);
    trilerp_sorted<<<grid, block, 0, stream>>>(x, values, px, py, pz, perm, out, K);
}

// Round 3
// 107.311 us; speedup vs baseline: 3.5179x; 3.5179x over previous
//
#include <hip/hip_runtime.h>

#define GRIDN 256
#define BPA 8                 // bins per axis (32 cells each)
#define NBINS (BPA * BPA * BPA)   // 512
#define CAP 6144              // slots per bin (expected max ~5100)
#define CURSOR_STRIDE 16      // one cursor per 64B line (atomic contention fix)

// ---------- shared helpers ----------

__device__ __forceinline__ int cell_guess(float c) {
    float t = (c + 0.64f) * 200.0f;
    int i = (int)t;
    return min(max(i, 0), GRIDN - 1);
}

// exact jnp.searchsorted(p, c, side='left') + clip semantics
__device__ __forceinline__ void dim_interp(float c, const float* __restrict__ p,
                                           int& il, int& ir, float& dl, float& dr) {
    const float SCALE = 0.005f;
    const float OFFSET = -0.64f;
    float t = (c - OFFSET) * (1.0f / SCALE);
    int i = (int)ceilf(t);
    i = min(max(i, 0), GRIDN - 1);
    while (i < GRIDN - 1 && p[i] < c) ++i;
    while (i > 0 && p[i - 1] >= c) --i;
    ir = i;
    il = max(i - 1, 0);
    dl = fmaxf(c - p[il], 0.0f);
    dr = fmaxf(p[ir] - c, 0.0f);
    if (dl == 0.0f && dr == 0.0f) { dl = 1.0f; dr = 1.0f; }
}

__device__ __forceinline__ float interp_point(float cx, float cy, float cz,
                                              const float* __restrict__ values,
                                              const float* __restrict__ px,
                                              const float* __restrict__ py,
                                              const float* __restrict__ pz) {
    int ixl, ixr, iyl, iyr, izl, izr;
    float dxl, dxr, dyl, dyr, dzl, dzr;
    dim_interp(cx, px, ixl, ixr, dxl, dxr);
    dim_interp(cy, py, iyl, iyr, dyl, dyr);
    dim_interp(cz, pz, izl, izr, dzl, dzr);

    int bxl = ixl << 16, bxr = ixr << 16;
    int byl = iyl << 8,  byr = iyr << 8;

    float v000 = values[bxl + byl + izl];
    float v001 = values[bxl + byl + izr];
    float v010 = values[bxl + byr + izl];
    float v011 = values[bxl + byr + izr];
    float v100 = values[bxr + byl + izl];
    float v101 = values[bxr + byl + izr];
    float v110 = values[bxr + byr + izl];
    float v111 = values[bxr + byr + izr];

    float num =
        v000 * (dxr * dyr * dzr) +
        v001 * (dxr * dyr * dzl) +
        v010 * (dxr * dyl * dzr) +
        v011 * (dxr * dyl * dzl) +
        v100 * (dxl * dyr * dzr) +
        v101 * (dxl * dyr * dzl) +
        v110 * (dxl * dyl * dzr) +
        v111 * (dxl * dyl * dzl);

    float den = (dxl + dxr) * (dyl + dyr) * (dzl + dzr);
    return num / den;
}

__device__ __forceinline__ int bin_of(float cx, float cy, float cz) {
    int bx = cell_guess(cx) >> 5;
    int by = cell_guess(cy) >> 5;
    int bz = cell_guess(cz) >> 5;
    return (bx * BPA + by) * BPA + bz;
}

// ---------- K0: init padded cursors ----------

__global__ void init_cursors(unsigned* __restrict__ cursor) {
    int t = blockIdx.x * blockDim.x + threadIdx.x;
    if (t < NBINS) cursor[t * CURSOR_STRIDE] = (unsigned)(t * CAP);
}

// ---------- K1: block-aggregated bin scatter (contention-free-ish) ----------

__global__ __launch_bounds__(1024) void bin_scatter2(
        const float* __restrict__ x, int K,
        unsigned* __restrict__ cursor,
        float4* __restrict__ records,
        int* __restrict__ inv,
        const float* __restrict__ values,
        const float* __restrict__ px,
        const float* __restrict__ py,
        const float* __restrict__ pz,
        float* __restrict__ out) {
    __shared__ unsigned cnt[NBINS];
    __shared__ unsigned slotcur[NBINS];

    int base = blockIdx.x * 4096;
    int end = min(base + 4096, K);

    for (int t = threadIdx.x; t < NBINS; t += 1024) cnt[t] = 0;
    __syncthreads();

    // phase A: count (x chunk stays L1/L2-hot for phase C reload)
    for (int i = base + threadIdx.x; i < end; i += 1024) {
        int b = bin_of(x[3 * i], x[3 * i + 1], x[3 * i + 2]);
        atomicAdd(&cnt[b], 1u);
    }
    __syncthreads();

    // phase B: one aggregated global atomic per bin per block (padded cursors)
    for (int t = threadIdx.x; t < NBINS; t += 1024)
        slotcur[t] = atomicAdd(&cursor[t * CURSOR_STRIDE], cnt[t]);
    __syncthreads();

    // phase C: write records coalesced-ish into reserved runs; inv coalesced by i
    for (int i = base + threadIdx.x; i < end; i += 1024) {
        float cx = x[3 * i], cy = x[3 * i + 1], cz = x[3 * i + 2];
        int b = bin_of(cx, cy, cz);
        unsigned s = atomicAdd(&slotcur[b], 1u);
        if (s < (unsigned)((b + 1) * CAP)) {
            records[s] = make_float4(cx, cy, cz, 0.0f);
            inv[i] = (int)s;
        } else {
            // bin overflow (statistically never): compute inline, mark done
            inv[i] = -1;
            out[i] = interp_point(cx, cy, cz, values, px, py, pz);
        }
    }
}

// ---------- K2: interpolate in bin-sorted order, sequential result writes ----------

__global__ void interp_sorted(const float4* __restrict__ records,
                              const unsigned* __restrict__ cursor,
                              const float* __restrict__ values,
                              const float* __restrict__ px,
                              const float* __restrict__ py,
                              const float* __restrict__ pz,
                              float* __restrict__ res) {
    // chunked bijective XCD swizzle: each XCD owns a contiguous slot range
    int nb = gridDim.x;
    int b = blockIdx.x;
    int q = nb >> 3, r = nb & 7;
    int xcd = b & 7, seq = b >> 3;
    int swb = (xcd < r ? xcd * (q + 1) : r * (q + 1) + (xcd - r) * q) + seq;

    int slot = swb * blockDim.x + threadIdx.x;
    int bin = slot / CAP;
    if (bin >= NBINS) return;
    unsigned segend = min(cursor[bin * CURSOR_STRIDE], (unsigned)((bin + 1) * CAP));
    if ((unsigned)slot >= segend) return;

    float4 rec = records[slot];
    res[slot] = interp_point(rec.x, rec.y, rec.z, values, px, py, pz);
}

// ---------- K3: unscatter results to original order ----------

__global__ void unscatter(const int* __restrict__ inv,
                          const float* __restrict__ res,
                          float* __restrict__ out, int K) {
    int i = blockIdx.x * blockDim.x + threadIdx.x;
    if (i >= K) return;
    int s = inv[i];
    if (s >= 0) out[i] = res[s];
}

// ---------- fallback: direct (round-1) kernel ----------

__global__ void trilerp_direct(const float* __restrict__ x,
                               const float* __restrict__ values,
                               const float* __restrict__ px,
                               const float* __restrict__ py,
                               const float* __restrict__ pz,
                               float* __restrict__ out, int K) {
    int i = blockIdx.x * blockDim.x + threadIdx.x;
    if (i >= K) return;
    out[i] = interp_point(x[3 * i], x[3 * i + 1], x[3 * i + 2], values, px, py, pz);
}

extern "C" void kernel_launch(void* const* d_in, const int* in_sizes, int n_in,
                              void* d_out, int out_size, void* d_ws, size_t ws_size,
                              hipStream_t stream) {
    const float* x      = (const float*)d_in[0];
    const float* values = (const float*)d_in[1];
    const float* px     = (const float*)d_in[2];
    const float* py     = (const float*)d_in[3];
    const float* pz     = (const float*)d_in[4];
    float* out = (float*)d_out;

    int K = in_sizes[0] / 3;

    size_t cursor_bytes  = (size_t)NBINS * CURSOR_STRIDE * 4;          // 32 KB
    size_t records_bytes = (size_t)NBINS * CAP * 16;                   // 50.3 MB
    size_t inv_bytes     = (size_t)K * 4;                              // 8 MB
    size_t res_bytes     = (size_t)NBINS * CAP * 4;                    // 12.6 MB
    size_t need = cursor_bytes + records_bytes + inv_bytes + res_bytes;

    if (ws_size < need) {
        int grid = (K + 255) / 256;
        trilerp_direct<<<grid, 256, 0, stream>>>(x, values, px, py, pz, out, K);
        return;
    }

    unsigned* cursor = (unsigned*)d_ws;
    float4* records  = (float4*)((char*)d_ws + cursor_bytes);
    int* inv         = (int*)((char*)d_ws + cursor_bytes + records_bytes);
    float* res       = (float*)((char*)d_ws + cursor_bytes + records_bytes + inv_bytes);

    init_cursors<<<2, 256, 0, stream>>>(cursor);

    int nblk1 = (K + 4095) / 4096;
    bin_scatter2<<<nblk1, 1024, 0, stream>>>(x, K, cursor, records, inv,
                                             values, px, py, pz, out);

    int nblk2 = (NBINS * CAP) / 256;   // CAP divisible by 256
    interp_sorted<<<nblk2, 256, 0, stream>>>(records, cursor, values, px, py, pz, res);

    int nblk3 = (K + 255) / 256;
    unscatter<<<nblk3, 256, 0, stream>>>(inv, res, out, K);
}